// Round 6
// baseline (351.265 us; speedup 1.0000x reference)
//
#include <hip/hip_runtime.h>
#include <math.h>
#include <stdint.h>

// Problem constants (B=4, S=4096, D=2048, E=64, K=8)
#define NTOK   16384      // B*S
#define DDIM   2048
#define NE     64
#define TOPK   8

#define THREADS 512
#define NWAVE   8
#define TOKPB   32        // tokens per block -> 512 blocks -> 2 resident/CU
#define BK      64        // K-chunk per stage
#define NCHUNK  (DDIM / BK)   // 32

// float4 slots per buffer:
//   x tile: 512 slots; slot = k4*32 + i*4 + tgs  holds x[tgs*8+i][k4*4..+3]
//   W tile: 1024 slots; slot = k*16 + (e4 ^ (k4&1))  holds W[k][e4*4..+3]
#define XSLOTS   512                  // 8 KiB
#define WSLOTS   1024                 // 16 KiB
#define BUFSLOTS (XSLOTS + WSLOTS)    // 1536 (24 KiB); x2 buffers = 48 KiB

// scoreBuf swizzle: logical [t][e] stored at t*67 + (e ^ (t&7))
#define SBIDX(t,e) ((t)*67 + ((e) ^ ((t) & 7)))

// Async global->LDS DMA, 16 B per lane; LDS dest = wave-uniform base + lane*16.
__device__ __forceinline__ void gl_lds16(const void* g, void* l) {
    __builtin_amdgcn_global_load_lds(
        (const __attribute__((address_space(1))) void*)(uintptr_t)g,
        (__attribute__((address_space(3))) void*)(uintptr_t)l,
        16, 0, 0);
}

__global__ __launch_bounds__(THREADS, 2) void gate_kernel(
    const float* __restrict__ x, const float* __restrict__ W,
    const float* __restrict__ b, float* __restrict__ out)
{
    __shared__ float4 smem[2 * BUFSLOTS];   // 48 KiB

    const int tid  = threadIdx.x;
    const int wave = tid >> 6;
    const int lane = tid & 63;
    // compute roles: intra-wave K-split. half-wave h handles k4 = wave*2+h.
    const int half = lane >> 5;
    const int tg   = (lane >> 3) & 3;  // 4 token groups of 8 tokens
    const int eg   = lane & 7;         // 8 expert groups of 8 experts
    const int k4   = wave * 2 + half;  // this lane's k-quad (0..15) per chunk
    const int tok0 = blockIdx.x * TOKPB;

    // ---- staging source addresses ----
    // x: lane's LDS slot = wave*64 + lane = tid -> k4s = tid>>5, r = tid&31,
    //    i = r>>2, tgs = r&3, token = tgs*8 + i.
    const int st_t = (tid & 3) * 8 + ((tid >> 2) & 7);
    const float* gx = x + (size_t)(tok0 + st_t) * DDIM + ((tid >> 5) << 2);
    // W: slots s0 = wave*128+lane, s1 = s0+64; k = s>>4, e4 = (s&15)^(k4&1).
    const int s0 = wave * 128 + lane;
    const int k0 = s0 >> 4, e40 = (s0 & 15) ^ ((k0 >> 2) & 1);
    const int s1 = s0 + 64;
    const int k1 = s1 >> 4, e41 = (s1 & 15) ^ ((k1 >> 2) & 1);
    const float* gw0 = W + (size_t)k0 * NE + e40 * 4;
    const float* gw1 = W + (size_t)k1 * NE + e41 * 4;

    float acc[8][8];
#pragma unroll
    for (int i = 0; i < 8; ++i)
#pragma unroll
        for (int j = 0; j < 8; ++j) acc[i][j] = 0.f;

    // stage chunk c into buffer c&1 (3 async 16B DMAs per lane, no VGPRs)
    auto stage = [&](int c) {
        float4* B = &smem[(c & 1) * BUFSLOTS];
        const int kc = c * BK;
        gl_lds16(gx + kc,                    &B[wave * 64]);
        gl_lds16(gw0 + (size_t)kc * NE,      &B[XSLOTS + wave * 128]);
        gl_lds16(gw1 + (size_t)kc * NE,      &B[XSLOTS + wave * 128 + 64]);
    };

    stage(0);
    __syncthreads();   // vmcnt drain -> buffer 0 ready

    for (int c = 0; c < NCHUNK; ++c) {
        if (c + 1 < NCHUNK) stage(c + 1);   // async into the other buffer
        const float4* BX = &smem[(c & 1) * BUFSLOTS];
        const float4* BW = BX + XSLOTS;

        // batch the 8 x-reads (one lgkm wait covers all; banks: 8 addrs over
        // 4 bank-groups = 2-way broadcast = free)
        float4 xv[8];
#pragma unroll
        for (int i = 0; i < 8; ++i)
            xv[i] = BX[k4 * 32 + i * 4 + tg];

#pragma unroll
        for (int kk = 0; kk < 4; ++kk) {
            const int k = k4 * 4 + kk;
            // storage col = e4 ^ (k4&1); halves hit disjoint bank-group
            // parities -> 2-way = free
            const float4 wa = BW[k * 16 + eg * 2 + half];
            const float4 wb = BW[k * 16 + eg * 2 + 1 - half];
            const float ws[8] = {wa.x, wa.y, wa.z, wa.w,
                                 wb.x, wb.y, wb.z, wb.w};
#pragma unroll
            for (int i = 0; i < 8; ++i) {
                const float xs = ((const float*)&xv[i])[kk];
#pragma unroll
                for (int j = 0; j < 8; ++j)
                    acc[i][j] = fmaf(xs, ws[j], acc[i][j]);
            }
        }
        __syncthreads();   // all waves done with buf c; buf c+1 DMA drained
    }

    // ---- cross-wave/half reduction into swizzled scoreBuf (aliases smem) ----
    float* sb = (float*)smem;
    for (int s = tid; s < TOKPB * 67; s += THREADS) sb[s] = 0.f;
    __syncthreads();
#pragma unroll
    for (int i = 0; i < 8; ++i)
#pragma unroll
        for (int j = 0; j < 8; ++j)
            atomicAdd(&sb[SBIDX(tg * 8 + i, eg * 8 + j)], acc[i][j]);
    __syncthreads();

    float* out_g   = out;                           // [16384][8]
    float* out_idx = out + (size_t)NTOK * TOPK;     // [16384][8] (as float)
    float* out_s   = out + (size_t)NTOK * TOPK * 2; // [16384][64]

    // ---- sigmoid + store scores; overwrite scoreBuf with sigmoid ----
#pragma unroll
    for (int r = 0; r < (TOKPB * NE) / THREADS; ++r) {
        const int flat = r * THREADS + tid;     // 0..2047
        const int t = flat >> 6;
        const int e = flat & 63;
        const float z = sb[SBIDX(t, e)] + b[e];
        const float s = 1.f / (1.f + expf(-z));
        out_s[(size_t)tok0 * NE + flat] = s;
        sb[SBIDX(t, e)] = s;
    }
    __syncthreads();

    // ---- top-8 per token (strict > picks lowest index on ties, matching
    // jax.lax.top_k) ----
    if (tid < TOKPB) {
        const int t = tid;
        float gv[TOPK];
        int   gi[TOPK];
        float sum = 0.f;
#pragma unroll
        for (int j = 0; j < TOPK; ++j) {
            float best = -1.f;
            int bi = 0;
            for (int e = 0; e < NE; ++e) {
                const float v = sb[SBIDX(t, e)];
                if (v > best) { best = v; bi = e; }
            }
            gv[j] = best; gi[j] = bi; sum += best;
            sb[SBIDX(t, bi)] = -2.f;  // sigmoid in (0,1), so excluded
        }
        const float inv = 1.f / sum;
#pragma unroll
        for (int j = 0; j < TOPK; ++j) {
            out_g[(size_t)(tok0 + t) * TOPK + j]   = gv[j] * inv;
            out_idx[(size_t)(tok0 + t) * TOPK + j] = (float)gi[j];
        }
    }
}

extern "C" void kernel_launch(void* const* d_in, const int* in_sizes, int n_in,
                              void* d_out, int out_size, void* d_ws, size_t ws_size,
                              hipStream_t stream) {
    const float* x = (const float*)d_in[0];
    const float* W = (const float*)d_in[1];
    const float* b = (const float*)d_in[2];
    // d_in[3] is k (==8), compile-time constant here.
    float* out = (float*)d_out;
    gate_kernel<<<NTOK / TOKPB, THREADS, 0, stream>>>(x, W, b, out);
}

// Round 7
// 328.266 us; speedup vs baseline: 1.0701x; 1.0701x over previous
//
#include <hip/hip_runtime.h>
#include <math.h>
#include <stdint.h>

// Problem constants (B=4, S=4096, D=2048, E=64, K=8)
#define NTOK   16384      // B*S
#define DDIM   2048
#define NE     64
#define TOPK   8

#define THREADS 1024      // 16 waves
#define NWAVE   16
#define TOKPB   64        // tokens per block; grid = 256 = 1 block/CU, 50% occ
#define KPW     (DDIM / NWAVE)   // 128 k per wave (K-split 16)

// scoreBuf swizzle: logical [t][e] stored at t*67 + (e ^ (t&7)).
// 67 = 3 mod 32 (odd, coprime): lanes t=0..63 at fixed e hit 2 lanes/bank max.
#define SBIDX(t,e) ((t)*67 + ((e) ^ ((t) & 7)))

// Constant-address-space view of W: uniform loads through this pointer are
// provably readonly+uniform -> compiler emits s_load_dwordx16 (W row lives in
// SGPRs; v_fmac reads it as the scalar operand -> zero LDS, zero VGPR cost).
typedef const __attribute__((address_space(4))) float* cfptr;

__global__ __launch_bounds__(THREADS, 1) void gate_kernel(
    const float* __restrict__ x, const float* __restrict__ W,
    const float* __restrict__ b, float* __restrict__ out)
{
    __shared__ float sb[TOKPB * 67];   // ~17 KiB score buffer

    const int tid  = threadIdx.x;
    const int t    = tid & 63;                              // lane = local token
    // readfirstlane makes the wave id PROVABLY uniform so W addresses
    // scalarize (tid>>6 alone is not uniform to the compiler).
    const int wv   = __builtin_amdgcn_readfirstlane(tid >> 6);
    const int tok0 = blockIdx.x * TOKPB;

    cfptr Wc = (cfptr)(uintptr_t)W;

    float acc[NE];
#pragma unroll
    for (int e = 0; e < NE; ++e) acc[e] = 0.f;

    // x: lane streams its own token row, float4 per 4 k (256 FMAs per load).
    // Lanes stride by the row pitch (uncoalesced) but each 64B line is fully
    // consumed by one lane across successive k4 -> L2/L3-served, ~4KiB/wave
    // working set. x (128 MiB) < L3 (256 MiB) -> warm replays are L3 hits.
    const float4* xrow = (const float4*)(x + (size_t)(tok0 + t) * DDIM + wv * KPW);

    for (int k4 = 0; k4 < KPW / 4; ++k4) {
        const float4 xv = xrow[k4];
        const float xs[4] = {xv.x, xv.y, xv.z, xv.w};
#pragma unroll
        for (int kk = 0; kk < 4; ++kk) {
            const int k = wv * KPW + k4 * 4 + kk;   // uniform
            cfptr wr = Wc + (size_t)k * NE;
#pragma unroll
            for (int e = 0; e < NE; ++e)
                acc[e] = fmaf(xs[kk], wr[e], acc[e]);
        }
    }

    // ---- reduce the 16 K-slices: LDS atomics into swizzled scoreBuf ----
    for (int s = tid; s < TOKPB * 67; s += THREADS) sb[s] = 0.f;
    __syncthreads();
#pragma unroll
    for (int e = 0; e < NE; ++e)
        atomicAdd(&sb[SBIDX(t, e)], acc[e]);
    __syncthreads();

    float* out_g   = out;                           // [16384][8]
    float* out_idx = out + (size_t)NTOK * TOPK;     // [16384][8] (as float)
    float* out_s   = out + (size_t)NTOK * TOPK * 2; // [16384][64]

    // ---- sigmoid + store scores; overwrite scoreBuf with sigmoid ----
#pragma unroll
    for (int r = 0; r < (TOKPB * NE) / THREADS; ++r) {
        const int flat = r * THREADS + tid;     // 0..4095
        const int tt = flat >> 6;
        const int e  = flat & 63;
        const float z = sb[SBIDX(tt, e)] + b[e];
        const float s = 1.f / (1.f + expf(-z));
        out_s[(size_t)tok0 * NE + flat] = s;
        sb[SBIDX(tt, e)] = s;
    }
    __syncthreads();

    // ---- top-8 per token (strict > picks lowest index on ties, matching
    // jax.lax.top_k) ----
    if (tid < TOKPB) {
        float gv[TOPK];
        int   gi[TOPK];
        float sum = 0.f;
#pragma unroll
        for (int j = 0; j < TOPK; ++j) {
            float best = -1.f;
            int bi = 0;
            for (int e = 0; e < NE; ++e) {
                const float v = sb[SBIDX(tid, e)];
                if (v > best) { best = v; bi = e; }
            }
            gv[j] = best; gi[j] = bi; sum += best;
            sb[SBIDX(tid, bi)] = -2.f;  // sigmoid in (0,1), so excluded
        }
        const float inv = 1.f / sum;
#pragma unroll
        for (int j = 0; j < TOPK; ++j) {
            out_g[(size_t)(tok0 + tid) * TOPK + j]   = gv[j] * inv;
            out_idx[(size_t)(tok0 + tid) * TOPK + j] = (float)gi[j];
        }
    }
}

extern "C" void kernel_launch(void* const* d_in, const int* in_sizes, int n_in,
                              void* d_out, int out_size, void* d_ws, size_t ws_size,
                              hipStream_t stream) {
    const float* x = (const float*)d_in[0];
    const float* W = (const float*)d_in[1];
    const float* b = (const float*)d_in[2];
    // d_in[3] is k (==8), compile-time constant here.
    float* out = (float*)d_out;
    gate_kernel<<<NTOK / TOKPB, THREADS, 0, stream>>>(x, W, b, out);
}